// Round 1
// baseline (555.506 us; speedup 1.0000x reference)
//
#include <hip/hip_runtime.h>

#define DF 64  // feature dim

// ---------------------------------------------------------------------------
// Phase 1: edge scatter. One wave (64 lanes) per edge: lane d does
//   summed[dst*64+d] += h[src*64+d];  lane 0 does deg[dst] += 1.
// Reads of h[src] are 256B contiguous per edge (coalesced within the wave).
// ---------------------------------------------------------------------------
__global__ __launch_bounds__(256) void sage_scatter(
    const float* __restrict__ h, const int* __restrict__ src,
    const int* __restrict__ dst, float* __restrict__ summed,
    float* __restrict__ deg, int E)
{
    int gid = blockIdx.x * 256 + threadIdx.x;
    int e = gid >> 6;
    if (e >= E) return;
    int lane = threadIdx.x & 63;
    int s = src[e];
    int d = dst[e];
    float v = h[(size_t)s * DF + lane];
    atomicAdd(&summed[(size_t)d * DF + lane], v);
    if (lane == 0) atomicAdd(&deg[d], 1.0f);
}

// ---------------------------------------------------------------------------
// Phase 2: per-node update. One wave per node, lane o computes output feat o.
//   bundle[o] = b[o] + sum_k x[k] * W[o][k],  x = [h_row, c_row] (128)
// W staged in LDS with row stride 132 dwords (132 % 4 == 0 keeps 16B align;
// 132 mod 32 = 4 makes the 64-lane ds_read_b128 bank-even).
// x staged in a per-wave LDS buffer; read back as same-address float4
// broadcasts (conflict-free). Wave-synchronous LDS: same wave writes then
// reads -> DS pipe processes in order, compiler inserts lgkmcnt waits.
// ---------------------------------------------------------------------------
#define WSTRIDE 132

__global__ __launch_bounds__(256) void sage_update(
    const float* __restrict__ h, const float* __restrict__ W,
    const float* __restrict__ b, const float* __restrict__ summed,
    const float* __restrict__ deg, float* __restrict__ out, int N)
{
    __shared__ float Wp[DF * WSTRIDE];   // ~33 KB
    __shared__ float bs[DF];
    __shared__ float xbuf[4][128];       // per-wave concat buffer

    for (int i = threadIdx.x; i < DF * 128; i += 256) {
        int o = i >> 7, k = i & 127;
        Wp[o * WSTRIDE + k] = W[i];
    }
    if (threadIdx.x < DF) bs[threadIdx.x] = b[threadIdx.x];
    __syncthreads();

    const int wave = threadIdx.x >> 6;
    const int lane = threadIdx.x & 63;
    const int gw = blockIdx.x * 4 + wave;
    const int nw = gridDim.x * 4;
    float* xb = xbuf[wave];
    const float* wrow = &Wp[lane * WSTRIDE];
    const float bias = bs[lane];

    for (int n = gw; n < N; n += nw) {
        float dg = deg[n];
        float hv = h[(size_t)n * DF + lane];
        float inv = 1.0f / fmaxf(dg, 1.0f);
        float cv = summed[(size_t)n * DF + lane] * inv;

        xb[lane] = hv;
        xb[DF + lane] = cv;
        // wave-synchronous LDS: no block barrier needed (single-wave producer)

        float y = bias;
        #pragma unroll
        for (int k = 0; k < 128; k += 4) {
            float4 xk = *(const float4*)&xb[k];     // broadcast read
            float4 wk = *(const float4*)&wrow[k];
            y += xk.x * wk.x;
            y += xk.y * wk.y;
            y += xk.z * wk.z;
            y += xk.w * wk.w;
        }

        // L2 norm across the 64 lanes (butterfly)
        float ss = y * y;
        #pragma unroll
        for (int m = 1; m < 64; m <<= 1) ss += __shfl_xor(ss, m);

        float norm = sqrtf(ss);
        float nb = y / fmaxf(norm, 1e-12f);
        float nh = fmaxf(nb, 0.0f);          // relu
        float hupd = (dg > 0.0f) ? nh : hv;  // DGL: untouched nodes keep h
        out[(size_t)n * DF + lane] = hv + hupd;  // residual
    }
}

extern "C" void kernel_launch(void* const* d_in, const int* in_sizes, int n_in,
                              void* d_out, int out_size, void* d_ws, size_t ws_size,
                              hipStream_t stream) {
    const float* h   = (const float*)d_in[0];
    const float* W   = (const float*)d_in[1];
    const float* b   = (const float*)d_in[2];
    const int*   src = (const int*)d_in[3];
    const int*   dst = (const int*)d_in[4];
    float* out = (float*)d_out;

    const int N = in_sizes[0] / DF;
    const int E = in_sizes[3];

    float* summed = (float*)d_ws;
    float* deg    = summed + (size_t)N * DF;

    // ws is poisoned 0xAA before every launch -> zero the accumulators
    hipMemsetAsync(d_ws, 0, (size_t)(N * DF + N) * sizeof(float), stream);

    // scatter: one wave per edge
    int scatter_blocks = (E + 3) / 4;  // 4 edges (waves) per 256-thread block
    sage_scatter<<<scatter_blocks, 256, 0, stream>>>(h, src, dst, summed, deg, E);

    // update: grid-stride over nodes, 4 waves (nodes) per block
    int update_blocks = 2048;
    sage_update<<<update_blocks, 256, 0, stream>>>(h, W, b, summed, deg, out, N);
}

// Round 2
// 422.679 us; speedup vs baseline: 1.3143x; 1.3143x over previous
//
#include <hip/hip_runtime.h>

#define DF 64       // feature dim
#define WSTRIDE 132 // LDS row stride for W (132%4==0 keeps 16B align; 132%32==4 spreads banks)

// ---------------------------------------------------------------------------
// CSR build pass 1: per-destination degree count (int atomics, 1/edge).
// ---------------------------------------------------------------------------
__global__ __launch_bounds__(256) void count_deg(
    const int* __restrict__ dst, int* __restrict__ cnt, int E)
{
    int e = blockIdx.x * 256 + threadIdx.x;
    if (e < E) atomicAdd(&cnt[dst[e]], 1);
}

// ---------------------------------------------------------------------------
// Scan pass 1: each block scans 1024 counts (4/thread), emits per-element
// block-local exclusive prefix + the block total.
// ---------------------------------------------------------------------------
__global__ __launch_bounds__(256) void scan_blk(
    const int* __restrict__ cnt, int* __restrict__ part,
    int* __restrict__ bsum, int N)
{
    __shared__ int wsum[4];
    int t = threadIdx.x, lane = t & 63, w = t >> 6;
    int base = blockIdx.x * 1024 + t * 4;
    int4 v = make_int4(0, 0, 0, 0);
    if (base + 3 < N) {
        v = *(const int4*)&cnt[base];
    } else {
        if (base     < N) v.x = cnt[base];
        if (base + 1 < N) v.y = cnt[base + 1];
        if (base + 2 < N) v.z = cnt[base + 2];
        if (base + 3 < N) v.w = cnt[base + 3];
    }
    int s = v.x + v.y + v.z + v.w;
    int sc = s;  // inclusive wave scan
    #pragma unroll
    for (int m = 1; m < 64; m <<= 1) {
        int u = __shfl_up(sc, m);
        if (lane >= m) sc += u;
    }
    if (lane == 63) wsum[w] = sc;
    __syncthreads();
    int woff = 0;
    for (int i = 0; i < w; ++i) woff += wsum[i];
    int excl = woff + sc - s;  // block-local exclusive prefix of this thread's chunk
    if (base     < N) part[base]     = excl;
    if (base + 1 < N) part[base + 1] = excl + v.x;
    if (base + 2 < N) part[base + 2] = excl + v.x + v.y;
    if (base + 3 < N) part[base + 3] = excl + v.x + v.y + v.z;
    if (t == 255) bsum[blockIdx.x] = woff + sc;  // block total
}

// ---------------------------------------------------------------------------
// Scan pass 2: single block scans the block totals (nb <= 256).
// ---------------------------------------------------------------------------
__global__ __launch_bounds__(256) void scan_top(
    const int* __restrict__ bsum, int* __restrict__ boff, int nb)
{
    __shared__ int wsum[4];
    int t = threadIdx.x, lane = t & 63, w = t >> 6;
    int v = (t < nb) ? bsum[t] : 0;
    int sc = v;
    #pragma unroll
    for (int m = 1; m < 64; m <<= 1) {
        int u = __shfl_up(sc, m);
        if (lane >= m) sc += u;
    }
    if (lane == 63) wsum[w] = sc;
    __syncthreads();
    int woff = 0;
    for (int i = 0; i < w; ++i) woff += wsum[i];
    if (t < nb) boff[t] = woff + sc - v;  // exclusive
}

// ---------------------------------------------------------------------------
// Scan pass 3: globalize, write offsets + mutable cursor copy.
// ---------------------------------------------------------------------------
__global__ __launch_bounds__(256) void scan_add(
    const int* __restrict__ part, const int* __restrict__ boff,
    int* __restrict__ offsets, int* __restrict__ cursor, int N, int E)
{
    int i = blockIdx.x * 256 + threadIdx.x;
    if (i < N) {
        int o = part[i] + boff[i >> 10];
        offsets[i] = o;
        cursor[i]  = o;
    }
    if (i == 0) offsets[N] = E;
}

// ---------------------------------------------------------------------------
// CSR build pass 2: scatter edge source ids into per-destination segments.
// ---------------------------------------------------------------------------
__global__ __launch_bounds__(256) void fill_csr(
    const int* __restrict__ src, const int* __restrict__ dst,
    int* __restrict__ cursor, int* __restrict__ eidx, int E)
{
    int e = blockIdx.x * 256 + threadIdx.x;
    if (e < E) {
        int p = atomicAdd(&cursor[dst[e]], 1);
        eidx[p] = src[e];
    }
}

// ---------------------------------------------------------------------------
// Fused gather + update. One wave per node, lane = feature index.
//   c = mean over neighbors of h[src];  y = concat(h,c)·W^T + b;
//   y /= ||y||; relu; where(deg>0); residual.
// Gather: 64 neighbor ids loaded coalesced, broadcast by shfl; 4 independent
// accumulators keep 4 gather loads in flight (latency hiding).
// Matmul: W staged in LDS (bank-padded rows), x staged per-wave in LDS and
// read back as same-address float4 broadcasts (conflict-free,
// wave-synchronous so no block barrier in the divergent loop).
// ---------------------------------------------------------------------------
__global__ __launch_bounds__(256) void sage_fused(
    const float* __restrict__ h, const float* __restrict__ W,
    const float* __restrict__ b, const int* __restrict__ offsets,
    const int* __restrict__ eidx, float* __restrict__ out, int N)
{
    __shared__ float Wp[DF * WSTRIDE];   // ~33 KB
    __shared__ float bs[DF];
    __shared__ float xbuf[4][128];

    for (int i = threadIdx.x; i < DF * 128; i += 256) {
        int o = i >> 7, k = i & 127;
        Wp[o * WSTRIDE + k] = W[i];
    }
    if (threadIdx.x < DF) bs[threadIdx.x] = b[threadIdx.x];
    __syncthreads();

    const int wave = threadIdx.x >> 6;
    const int lane = threadIdx.x & 63;
    const int gw = blockIdx.x * 4 + wave;
    const int nw = gridDim.x * 4;
    float* xb = xbuf[wave];
    const float* wrow = &Wp[lane * WSTRIDE];
    const float bias = bs[lane];

    for (int n = gw; n < N; n += nw) {
        int beg = offsets[n];
        int end = offsets[n + 1];
        float hv = h[(size_t)n * DF + lane];

        // --- gather-sum neighbors ---
        float a0 = 0.f, a1 = 0.f, a2 = 0.f, a3 = 0.f;
        for (int base = beg; base < end; base += 64) {
            int m = end - base;
            if (m > 64) m = 64;
            int idx = 0;
            if (lane < m) idx = eidx[base + lane];
            int j = 0;
            for (; j + 3 < m; j += 4) {
                int s0 = __shfl(idx, j);
                int s1 = __shfl(idx, j + 1);
                int s2 = __shfl(idx, j + 2);
                int s3 = __shfl(idx, j + 3);
                a0 += h[(size_t)s0 * DF + lane];
                a1 += h[(size_t)s1 * DF + lane];
                a2 += h[(size_t)s2 * DF + lane];
                a3 += h[(size_t)s3 * DF + lane];
            }
            for (; j < m; ++j) {
                int s0 = __shfl(idx, j);
                a0 += h[(size_t)s0 * DF + lane];
            }
        }
        float dg = (float)(end - beg);
        float cv = ((a0 + a1) + (a2 + a3)) / fmaxf(dg, 1.0f);

        // --- update: y = [h,c]·W^T + b ---
        xb[lane] = hv;
        xb[DF + lane] = cv;   // wave-synchronous LDS, no block barrier needed

        float y = bias;
        #pragma unroll
        for (int k = 0; k < 128; k += 4) {
            float4 xk = *(const float4*)&xb[k];    // same-address broadcast
            float4 wk = *(const float4*)&wrow[k];
            y += xk.x * wk.x;
            y += xk.y * wk.y;
            y += xk.z * wk.z;
            y += xk.w * wk.w;
        }

        // L2 norm across 64 lanes
        float ss = y * y;
        #pragma unroll
        for (int m = 1; m < 64; m <<= 1) ss += __shfl_xor(ss, m);

        float norm = sqrtf(ss);
        float nb = y / fmaxf(norm, 1e-12f);
        float nh = fmaxf(nb, 0.0f);
        float hupd = (dg > 0.0f) ? nh : hv;
        out[(size_t)n * DF + lane] = hv + hupd;
    }
}

extern "C" void kernel_launch(void* const* d_in, const int* in_sizes, int n_in,
                              void* d_out, int out_size, void* d_ws, size_t ws_size,
                              hipStream_t stream) {
    const float* h   = (const float*)d_in[0];
    const float* W   = (const float*)d_in[1];
    const float* b   = (const float*)d_in[2];
    const int*   src = (const int*)d_in[3];
    const int*   dst = (const int*)d_in[4];
    float* out = (float*)d_out;

    const int N = in_sizes[0] / DF;
    const int E = in_sizes[3];

    // workspace carve (ints, 16B-aligned sections)
    int* cnt     = (int*)d_ws;                 // N
    int* part    = cnt     + ((N + 15) & ~15); // N
    int* bsum    = part    + ((N + 15) & ~15); // 256
    int* boff    = bsum    + 256;              // 256
    int* offsets = boff    + 256;              // N+1
    int* cursor  = offsets + ((N + 16) & ~15); // N
    int* eidx    = cursor  + ((N + 15) & ~15); // E

    // zero the degree counters (ws is poisoned 0xAA before every launch)
    hipMemsetAsync(cnt, 0, (size_t)N * sizeof(int), stream);

    int eb = (E + 255) / 256;
    count_deg<<<eb, 256, 0, stream>>>(dst, cnt, E);

    int nb = (N + 1023) / 1024;  // blocks in scan_blk (<= 256 for N <= 256K)
    scan_blk<<<nb, 256, 0, stream>>>(cnt, part, bsum, N);
    scan_top<<<1, 256, 0, stream>>>(bsum, boff, nb);
    scan_add<<<(N + 255) / 256, 256, 0, stream>>>(part, boff, offsets, cursor, N, E);

    fill_csr<<<eb, 256, 0, stream>>>(src, dst, cursor, eidx, E);

    sage_fused<<<2048, 256, 0, stream>>>(h, W, b, offsets, eidx, out, N);
}